// Round 4
// baseline (261.612 us; speedup 1.0000x reference)
//
#include <hip/hip_runtime.h>
#include <math.h>

// ---------------------------------------------------------------------------
// Performer encoder layer, MI355X round-3: 256-tile 8-wave double-buffered
// 2-phase GEMM (gemm256) for QKV/FFN1/FFN2; QKV fused to one GEMM (N=1536).
// N=8192, D=512, H=8, DH=64, NF=266 (padded to NFP=320 = 5*64).
// Workspace layout (bytes):
//   0         wtqkv  bf16 [1536][512]  (wq^T,wk^T,wv^T stacked)
//   1572864   wot    bf16 [512][512]
//   2097152   w1t    bf16 [2048][512]
//   4194304   w2t    bf16 [512][2048]
//   6291456   projb  bf16 [320][64]
//   6332416   h_bf   bf16 [8192][512]     (reused as attn_bf)
//   14721024  qkv    bf16 [8192][1536]  q=cols 0-511, k=512-1023, v=1024-1535
//                                        (reused as h2_bf)
//   39886848  diag   f32  [2][8][8192]
//   40411136  qp     bf16 [8][8192][320]
//   82354176  kpT    bf16 [8][320][8192]
//   124297216 mk     u32  [8]
//   124297472 vT     bf16 [8][64][8192]
//   132686080 part   f32  [8][32][64][320]
//   153657600 ksum   f32  [8][320]
//   153667840 ctxpad bf16 [8][96][320]   (rows 0-63 ctx^T, row 64 ksum, 65+ 0)
//   130468096 gbf    bf16 [8192][2048]   (overlaps vT/part/ksum/ctxpad;
//                                         lifetimes disjoint: all dead pre-FFN1)
//   total 164022528 B.  xb (f32 [8192][512]) lives in d_out.
// ---------------------------------------------------------------------------

typedef __attribute__((ext_vector_type(8))) short bf16x8;
typedef __attribute__((ext_vector_type(4))) float f32x4;

#define N_SEQ 8192
#define DMODEL 512
#define DQKV 1536
#define NHEAD 8
#define DHEAD 64
#define NF 266
#define NFP 320
#define PEPS 1e-4f
#define LNEPS 1e-5f
#define DNORM 0.35355339059327373f
#define RATIO 0.06131393694f

__device__ __forceinline__ unsigned short f2bf(float f) {
  unsigned u = __float_as_uint(f);
  u += 0x7FFFu + ((u >> 16) & 1u);
  return (unsigned short)(u >> 16);
}
__device__ __forceinline__ float bf2f(unsigned short b) {
  return __uint_as_float(((unsigned)b) << 16);
}
__device__ __forceinline__ unsigned enc_f32(float f) {
  unsigned i = __float_as_uint(f);
  return (i & 0x80000000u) ? ~i : (i | 0x80000000u);
}
__device__ __forceinline__ float dec_f32(unsigned u) {
  return (u & 0x80000000u) ? __uint_as_float(u & 0x7FFFFFFFu) : __uint_as_float(~u);
}

// async global->LDS, 16B per lane. LDS dest must be wave-uniform base; HW adds
// lane*16. Global source is per-lane (pre-swizzled by caller).
__device__ __forceinline__ void g2l16(const void* g, void* l) {
  __builtin_amdgcn_global_load_lds(
      (const __attribute__((address_space(1))) void*)g,
      (__attribute__((address_space(3))) void*)l, 16, 0, 0);
}

// -------------------- small prep kernels --------------------

__global__ void init_mk_kernel(unsigned* mk) {
  if (threadIdx.x < NHEAD) mk[threadIdx.x] = 0x007FFFFFu;  // enc(-inf)
}

// dst[c][r] = bf16(src[r][c]); src is [R][C] f32. grid (C/32, R/32), block (32,8)
__global__ __launch_bounds__(256) void transpose_w_kernel(const float* __restrict__ src,
                                                          unsigned short* __restrict__ dst,
                                                          int R, int C) {
  __shared__ float tile[32][33];
  int c0 = blockIdx.x * 32, r0 = blockIdx.y * 32;
  int tx = threadIdx.x, ty = threadIdx.y;
  #pragma unroll
  for (int i = ty; i < 32; i += 8)
    tile[i][tx] = src[(long)(r0 + i) * C + c0 + tx];
  __syncthreads();
  #pragma unroll
  for (int i = ty; i < 32; i += 8)
    dst[(long)(c0 + i) * R + r0 + tx] = f2bf(tile[tx][i]);
}

__global__ void projb_kernel(const float* __restrict__ proj, unsigned short* __restrict__ pb) {
  int id = blockIdx.x * 256 + threadIdx.x;  // < 320*64
  int j = id >> 6;
  pb[id] = (j < NF) ? f2bf(proj[(long)j * 64 + (id & 63)] * DNORM) : (unsigned short)0;
}

// v slice of qkv [8192][1536] -> vT [8][64][8192].  grid (1,128,8), block 256.
__global__ __launch_bounds__(256) void vtrans_kernel(const unsigned short* __restrict__ v,
                                                     unsigned short* __restrict__ vT) {
  __shared__ unsigned short tl[64][66];
  int h = blockIdx.z, n0 = blockIdx.y * 64;
  int tid = threadIdx.x;
  int i = tid >> 2, c0 = (tid & 3) * 16;
  const unsigned short* src = v + (long)(n0 + i) * DQKV + h * DHEAD + c0;
  uint4 u0 = *(const uint4*)src;
  uint4 u1 = *(const uint4*)(src + 8);
  const unsigned short* e0 = (const unsigned short*)&u0;
  const unsigned short* e1 = (const unsigned short*)&u1;
  #pragma unroll
  for (int k = 0; k < 8; ++k) { tl[i][c0 + k] = e0[k]; tl[i][c0 + 8 + k] = e1[k]; }
  __syncthreads();
  unsigned short tmp[16];
  #pragma unroll
  for (int k = 0; k < 16; ++k) tmp[k] = tl[c0 + k][i];
  unsigned short* dst = vT + ((long)h * DHEAD + i) * N_SEQ + n0 + c0;
  *(uint4*)dst = *(uint4*)&tmp[0];
  *(uint4*)(dst + 8) = *(uint4*)&tmp[8];
}

// -------------------- layernorm --------------------

__global__ __launch_bounds__(256) void ln_kernel(const float* __restrict__ x,
                                                 const float* __restrict__ g,
                                                 const float* __restrict__ b,
                                                 unsigned short* __restrict__ out) {
  __shared__ float sred[4];
  int row = blockIdx.x, t = threadIdx.x;
  float2 v = ((const float2*)(x + (long)row * DMODEL))[t];
  float s = v.x + v.y;
  #pragma unroll
  for (int m = 32; m >= 1; m >>= 1) s += __shfl_xor(s, m);
  if ((t & 63) == 0) sred[t >> 6] = s;
  __syncthreads();
  float mu = (sred[0] + sred[1] + sred[2] + sred[3]) * (1.0f / DMODEL);
  __syncthreads();
  float d0 = v.x - mu, d1 = v.y - mu;
  float q = d0 * d0 + d1 * d1;
  #pragma unroll
  for (int m = 32; m >= 1; m >>= 1) q += __shfl_xor(q, m);
  if ((t & 63) == 0) sred[t >> 6] = q;
  __syncthreads();
  float var = (sred[0] + sred[1] + sred[2] + sred[3]) * (1.0f / DMODEL);
  float inv = rsqrtf(var + LNEPS);
  int c = t * 2;
  unsigned short o0 = f2bf(d0 * inv * g[c] + b[c]);
  unsigned short o1 = f2bf(d1 * inv * g[c + 1] + b[c + 1]);
  ((unsigned*)(out + (long)row * DMODEL))[t] = ((unsigned)o1 << 16) | o0;
}

enum { EPI_BF16 = 0, EPI_CTX = 1, EPI_BIAS_RES_F32 = 2, EPI_BIAS_GELU = 3 };

// -------------------- 256-tile 8-wave double-buffered GEMM --------------------
// C[M,N] = A[M,K] x Bt[N,K]^T. 512 threads = 8 waves (2M x 4N). BK=64.
// 2-phase pipeline: stage K-tile t+1 into buf^1 (global_load_lds), compute
// tile t from buf, single vmcnt/barrier drain per tile (T3/T4 minimum form).

template <int BM, int BN, int EPI>
__global__ __launch_bounds__(512, 2) void gemm256_kernel(
    const unsigned short* __restrict__ A, int lda,
    const unsigned short* __restrict__ Bt, int ldb,
    void* __restrict__ Cv, int ldc,
    int K,
    const float* __restrict__ bias,
    const float* __restrict__ res, int ldr) {
  constexpr int WM = BM / 2, WN = BN / 4;
  constexpr int MR = WM / 16, NR = WN / 16;
  constexpr int AIT = BM * 8 / 512;
  constexpr int BIT = BN * 8 / 512;
  const int tid = threadIdx.x;
  const int wave = tid >> 6, lane = tid & 63;
  const int lr = lane & 15, lg = lane >> 4;
  const int wr = wave >> 2, wc = wave & 3;
  const int m0 = blockIdx.x * BM, n0 = blockIdx.y * BN;

  __shared__ uint4 a_s[2][BM * 8];
  __shared__ uint4 b_s[2][BN * 8];

  const unsigned short* asrc[AIT];
  #pragma unroll
  for (int e = 0; e < AIT; ++e) {
    int chunk = e * 512 + tid;
    int r = chunk >> 3, c = chunk & 7;
    asrc[e] = A + (long)(m0 + r) * lda + (c ^ (r & 7)) * 8;
  }
  const unsigned short* bsrc[BIT];
  #pragma unroll
  for (int e = 0; e < BIT; ++e) {
    int chunk = e * 512 + tid;
    int r = chunk >> 3, c = chunk & 7;
    bsrc[e] = Bt + (long)(n0 + r) * ldb + (c ^ (r & 7)) * 8;
  }
  const int wbase = tid & 448;  // wave-uniform lane-block base

  f32x4 acc[MR][NR] = {};

  auto stage = [&](int buf, int t) {
    #pragma unroll
    for (int e = 0; e < AIT; ++e)
      g2l16(asrc[e] + t * 64, &a_s[buf][e * 512 + wbase]);
    #pragma unroll
    for (int e = 0; e < BIT; ++e)
      g2l16(bsrc[e] + t * 64, &b_s[buf][e * 512 + wbase]);
  };
  auto compute = [&](int buf) {
    #pragma unroll
    for (int ks = 0; ks < 2; ++ks) {
      bf16x8 af[MR], bv[NR];
      #pragma unroll
      for (int i = 0; i < MR; ++i) {
        int r = wr * WM + i * 16 + lr;
        af[i] = *(const bf16x8*)&a_s[buf][r * 8 + ((ks * 4 + lg) ^ (r & 7))];
      }
      #pragma unroll
      for (int j = 0; j < NR; ++j) {
        int r = wc * WN + j * 16 + lr;
        bv[j] = *(const bf16x8*)&b_s[buf][r * 8 + ((ks * 4 + lg) ^ (r & 7))];
      }
      #pragma unroll
      for (int i = 0; i < MR; ++i)
        #pragma unroll
        for (int j = 0; j < NR; ++j)
          acc[i][j] = __builtin_amdgcn_mfma_f32_16x16x32_bf16(af[i], bv[j], acc[i][j], 0, 0, 0);
    }
  };

  const int NT = K >> 6;
  stage(0, 0);
  __syncthreads();
  int cur = 0;
  for (int t = 0; t < NT - 1; ++t) {
    stage(cur ^ 1, t + 1);
    compute(cur);
    __syncthreads();
    cur ^= 1;
  }
  compute(cur);

  #pragma unroll
  for (int i = 0; i < MR; ++i) {
    #pragma unroll
    for (int j = 0; j < NR; ++j) {
      int gn = n0 + wc * WN + j * 16 + lr;
      #pragma unroll
      for (int rg = 0; rg < 4; ++rg) {
        int gm = m0 + wr * WM + i * 16 + lg * 4 + rg;
        float v = acc[i][j][rg];
        if (EPI == EPI_BF16) {
          ((unsigned short*)Cv)[(long)gm * ldc + gn] = f2bf(v);
        } else if (EPI == EPI_BIAS_RES_F32) {
          v += bias[gn] + res[(long)gm * ldr + gn];
          ((float*)Cv)[(long)gm * ldc + gn] = v;
        } else if (EPI == EPI_BIAS_GELU) {
          v += bias[gn];
          float t3 = 0.7978845608028654f * (v + 0.044715f * v * v * v);
          v = 0.5f * v * (1.0f + tanhf(t3));
          ((unsigned short*)Cv)[(long)gm * ldc + gn] = f2bf(v);
        }
      }
    }
  }
}

// -------------------- 128-tile 4-wave GEMM (small shapes) --------------------
// EPI_CTX: Bt has 96 rows (64 ctx + ksum row at 64 + zeros); epilogue divides
// cols 0..63 by the col-64 dot product (d = qp . ksum), broadcast via shfl.

template <int BM, int BN, int WM, int WN, int EPI>
__global__ __launch_bounds__(256) void gemm_kernel(
    const unsigned short* __restrict__ A, int lda, long sA,
    const unsigned short* __restrict__ Bt, int ldb, long sB,
    void* __restrict__ Cv, int ldc, long sC,
    int K,
    const float* __restrict__ bias,
    const float* __restrict__ res, int ldr) {
  constexpr int BK = 64;
  static_assert((BM / WM) * (BN / WN) == 4, "need 4 waves");
  constexpr int MR = WM / 16, NR = WN / 16;
  constexpr int WNN = BN / WN;
  constexpr int AIT = BM * 8 / 256;
  constexpr int BIT = BN * 8 / 256;
  const int tid = threadIdx.x;
  const int wave = tid >> 6, lane = tid & 63;
  const int lr = lane & 15, lg = lane >> 4;
  const int wr = wave / WNN, wc = wave % WNN;
  const int m0 = blockIdx.x * BM, n0 = blockIdx.y * BN;
  const int z = blockIdx.z;
  A += (long)z * sA;
  Bt += (long)z * sB;

  __shared__ uint4 a_s4[BM * 8];
  __shared__ uint4 b_s4[BN * 8];

  const unsigned short* asrc[AIT];
  #pragma unroll
  for (int e = 0; e < AIT; ++e) {
    int chunk = e * 256 + tid;
    int r = chunk >> 3, c = chunk & 7;
    asrc[e] = A + (long)(m0 + r) * lda + (c ^ (r & 7)) * 8;
  }
  const unsigned short* bsrc[BIT];
  #pragma unroll
  for (int e = 0; e < BIT; ++e) {
    int chunk = e * 256 + tid;
    int r = chunk >> 3, c = chunk & 7;
    bsrc[e] = Bt + (long)(n0 + r) * ldb + (c ^ (r & 7)) * 8;
  }
  const int wbase = tid & 192;

  f32x4 acc[MR][NR] = {};

  for (int k0 = 0; k0 < K; k0 += BK) {
    #pragma unroll
    for (int e = 0; e < AIT; ++e)
      g2l16(asrc[e] + k0, a_s4 + e * 256 + wbase);
    #pragma unroll
    for (int e = 0; e < BIT; ++e)
      g2l16(bsrc[e] + k0, b_s4 + e * 256 + wbase);
    __syncthreads();
    #pragma unroll
    for (int ks = 0; ks < 2; ++ks) {
      bf16x8 af[MR], bv[NR];
      #pragma unroll
      for (int i = 0; i < MR; ++i) {
        int r = wr * WM + i * 16 + lr;
        af[i] = *(const bf16x8*)&a_s4[r * 8 + ((ks * 4 + lg) ^ (r & 7))];
      }
      #pragma unroll
      for (int j = 0; j < NR; ++j) {
        int r = wc * WN + j * 16 + lr;
        bv[j] = *(const bf16x8*)&b_s4[r * 8 + ((ks * 4 + lg) ^ (r & 7))];
      }
      #pragma unroll
      for (int i = 0; i < MR; ++i)
        #pragma unroll
        for (int j = 0; j < NR; ++j)
          acc[i][j] = __builtin_amdgcn_mfma_f32_16x16x32_bf16(af[i], bv[j], acc[i][j], 0, 0, 0);
    }
    __syncthreads();
  }

  if constexpr (EPI == EPI_CTX) {
    #pragma unroll
    for (int i = 0; i < MR; ++i) {
      #pragma unroll
      for (int rg = 0; rg < 4; ++rg) {
        float dv = __shfl(acc[i][4][rg], lane & 48);  // col 64 (lr==0 lane)
        float inv = 1.0f / dv;
        int gm = m0 + wr * WM + i * 16 + lg * 4 + rg;
        #pragma unroll
        for (int j = 0; j < 4; ++j) {
          int gn = j * 16 + lr;  // cols 0..63
          ((unsigned short*)Cv)[(long)z * sC + (long)gm * ldc + gn] =
              f2bf(acc[i][j][rg] * inv);
        }
      }
    }
    return;
  }

  #pragma unroll
  for (int i = 0; i < MR; ++i) {
    #pragma unroll
    for (int j = 0; j < NR; ++j) {
      int gn = n0 + wc * WN + j * 16 + lr;
      #pragma unroll
      for (int rg = 0; rg < 4; ++rg) {
        int gm = m0 + wr * WM + i * 16 + lg * 4 + rg;
        float v = acc[i][j][rg];
        if (EPI == EPI_BF16) {
          ((unsigned short*)Cv)[(long)z * sC + (long)gm * ldc + gn] = f2bf(v);
        } else if (EPI == EPI_BIAS_RES_F32) {
          v += bias[gn] + res[(long)gm * ldr + gn];
          ((float*)Cv)[(long)z * sC + (long)gm * ldc + gn] = v;
        }
      }
    }
  }
}

// -------------------- diag: 0.5*dnorm^2*sum(q^2 or k^2) --------------------

__global__ __launch_bounds__(256) void diag_kernel(const unsigned short* __restrict__ qkv,
                                                   float* __restrict__ diag) {
  int id = blockIdx.x * 256 + threadIdx.x;  // < 2*8*8192
  int tensor = id >> 16;
  int rem = id & 65535;
  int n = rem >> 3, h = rem & 7;
  const unsigned short* p = qkv + tensor * DMODEL + (long)n * DQKV + h * DHEAD;
  float s = 0.f;
  #pragma unroll
  for (int c = 0; c < 8; ++c) {
    uint4 u = *(const uint4*)(p + c * 8);
    const unsigned short* e = (const unsigned short*)&u;
    #pragma unroll
    for (int i = 0; i < 8; ++i) { float f = bf2f(e[i]); s += f * f; }
  }
  diag[(long)tensor * 65536 + (long)h * N_SEQ + n] = s * 0.0625f;  // *0.5*dnorm^2
}

// -------------------- phi: dd GEMM + epilogue --------------------
// MODE 0: q -> qp row-major [h][n][NFP] (per-row max).
// MODE 1: k max pass (atomicMax enc).
// MODE 2: k exp pass -> kpT [h][NFP][N] (transposed write via LDS).

template <int MODE>
__global__ __launch_bounds__(256) void phi_kernel(
    const unsigned short* __restrict__ QK,  // [8192][1536] slice (q or k cols)
    const unsigned short* __restrict__ pb,  // [320][64]
    unsigned short* __restrict__ out,       // qp or kpT
    const float* __restrict__ diag,         // [8][8192]
    unsigned* __restrict__ mk) {
  const int tid = threadIdx.x;
  const int wave = tid >> 6, lane = tid & 63;
  const int lr = lane & 15, lg = lane >> 4;
  const int h = blockIdx.z;
  const int m0 = blockIdx.x * 64;

  __shared__ uint4 smem[3072];       // a(512) + b(2560); reused as kt32 in MODE 2
  __shared__ float sred[4];
  uint4* a_s4 = smem;
  uint4* b_s4 = smem + 512;

  const unsigned short* Aq = QK + (long)m0 * DQKV + h * DHEAD;
  const int wbase = tid & 192;

  #pragma unroll
  for (int e = 0; e < 2; ++e) {
    int chunk = e * 256 + tid;
    int r = chunk >> 3, c = chunk & 7;
    g2l16(Aq + (long)r * DQKV + (c ^ (r & 7)) * 8, a_s4 + e * 256 + wbase);
  }
  #pragma unroll
  for (int e = 0; e < 10; ++e) {
    int chunk = e * 256 + tid;
    int r = chunk >> 3, c = chunk & 7;
    g2l16(pb + (long)r * DHEAD + (c ^ (r & 7)) * 8, b_s4 + e * 256 + wbase);
  }
  __syncthreads();

  f32x4 acc[20] = {};
  #pragma unroll
  for (int ks = 0; ks < 2; ++ks) {
    int rA = wave * 16 + lr;
    bf16x8 af = *(const bf16x8*)&a_s4[rA * 8 + ((ks * 4 + lg) ^ (rA & 7))];
    #pragma unroll
    for (int j = 0; j < 20; ++j) {
      int rB = j * 16 + lr;
      bf16x8 bv = *(const bf16x8*)&b_s4[rB * 8 + ((ks * 4 + lg) ^ (rB & 7))];
      acc[j] = __builtin_amdgcn_mfma_f32_16x16x32_bf16(af, bv, acc[j], 0, 0, 0);
    }
  }

  const int gmb = m0 + wave * 16 + lg * 4;  // + rg

  if (MODE == 1) {
    float m = -3.0e38f;
    #pragma unroll
    for (int j = 0; j < 17; ++j) {
      bool valid = (j < 16) || (lr < 10);  // col = j*16+lr < 266
      if (valid) {
        #pragma unroll
        for (int rg = 0; rg < 4; ++rg) m = fmaxf(m, acc[j][rg]);
      }
    }
    #pragma unroll
    for (int s = 1; s < 64; s <<= 1) m = fmaxf(m, __shfl_xor(m, s));
    if (lane == 0) sred[wave] = m;
    __syncthreads();
    if (tid == 0) {
      float mm = fmaxf(fmaxf(sred[0], sred[1]), fmaxf(sred[2], sred[3]));
      atomicMax(&mk[h], enc_f32(mm));
    }
    return;
  }

  float dg[4];
  #pragma unroll
  for (int rg = 0; rg < 4; ++rg) dg[rg] = diag[(long)h * N_SEQ + gmb + rg];

  if (MODE == 0) {
    float mrow[4];
    #pragma unroll
    for (int rg = 0; rg < 4; ++rg) mrow[rg] = -3.0e38f;
    #pragma unroll
    for (int j = 0; j < 17; ++j) {
      bool valid = (j < 16) || (lr < 10);
      if (valid) {
        #pragma unroll
        for (int rg = 0; rg < 4; ++rg) mrow[rg] = fmaxf(mrow[rg], acc[j][rg]);
      }
    }
    #pragma unroll
    for (int s = 1; s < 16; s <<= 1)
      #pragma unroll
      for (int rg = 0; rg < 4; ++rg) mrow[rg] = fmaxf(mrow[rg], __shfl_xor(mrow[rg], s));

    #pragma unroll
    for (int j = 0; j < 20; ++j) {
      int col = j * 16 + lr;
      #pragma unroll
      for (int rg = 0; rg < 4; ++rg) {
        float v = 0.f;
        if (col < NF) v = RATIO * (expf(acc[j][rg] - dg[rg] - mrow[rg]) + PEPS);
        out[((long)h * N_SEQ + gmb + rg) * NFP + col] = f2bf(v);
      }
    }
  } else {
    // MODE 2: exp with global max, transposed write kpT[h][col][n]
    float mh = dec_f32(mk[h]);
    unsigned* kt32 = (unsigned*)smem;  // [320][33] uints (pairs of bf16 along n)
    __syncthreads();                   // a_s4/b_s4 reads done
    #pragma unroll
    for (int j = 0; j < 20; ++j) {
      int col = j * 16 + lr;
      #pragma unroll
      for (int p = 0; p < 2; ++p) {
        float v0 = 0.f, v1 = 0.f;
        if (col < NF) {
          v0 = RATIO * (expf(acc[j][2 * p] - dg[2 * p] - mh) + PEPS);
          v1 = RATIO * (expf(acc[j][2 * p + 1] - dg[2 * p + 1] - mh) + PEPS);
        }
        kt32[col * 33 + wave * 8 + lg * 2 + p] =
            (unsigned)f2bf(v0) | ((unsigned)f2bf(v1) << 16);
      }
    }
    __syncthreads();
    #pragma unroll
    for (int it = 0; it < 10; ++it) {
      int r = it * 32 + (tid >> 3);
      int cu = (tid & 7) * 4;
      uint4 o;
      o.x = kt32[r * 33 + cu + 0];
      o.y = kt32[r * 33 + cu + 1];
      o.z = kt32[r * 33 + cu + 2];
      o.w = kt32[r * 33 + cu + 3];
      *(uint4*)(out + ((long)h * NFP + r) * N_SEQ + m0 + cu * 2) = o;
    }
  }
}

// -------------------- ksum[h][j] = sum_n kpT[h][j][n] --------------------

__global__ __launch_bounds__(256) void ksum_kernel(const unsigned short* __restrict__ kpT,
                                                   float* __restrict__ ksum) {
  int h = blockIdx.y;
  int j = blockIdx.x * 4 + (threadIdx.x >> 6);
  int lane = threadIdx.x & 63;
  const unsigned short* row = kpT + ((long)h * NFP + j) * N_SEQ;
  float s = 0.f;
  #pragma unroll 4
  for (int it = 0; it < 16; ++it) {
    uint4 u = *(const uint4*)(row + (it * 64 + lane) * 8);
    const unsigned short* e = (const unsigned short*)&u;
    #pragma unroll
    for (int i = 0; i < 8; ++i) s += bf2f(e[i]);
  }
  #pragma unroll
  for (int m = 32; m >= 1; m >>= 1) s += __shfl_xor(s, m);
  if (lane == 0) ksum[h * NFP + j] = s;
}

// -------------------- ctx split-K MFMA: part[h][kc] = vT chunk x kpT chunk ----

__global__ __launch_bounds__(256) void ctx_mfma_kernel(
    const unsigned short* __restrict__ vT,   // [8][64][8192]
    const unsigned short* __restrict__ kpT,  // [8][320][8192]
    float* __restrict__ part) {              // [8][32][64][320]
  const int tid = threadIdx.x;
  const int wave = tid >> 6, lane = tid & 63;
  const int lr = lane & 15, lg = lane >> 4;
  const int wr = wave >> 1, wc = wave & 1;  // WM=32, WN=160
  const int kc = blockIdx.x, h = blockIdx.y;

  __shared__ uint4 a_s4[64 * 8];
  __shared__ uint4 b_s4[NFP * 8];

  const unsigned short* A = vT + (long)h * DHEAD * N_SEQ + kc * 256;
  const unsigned short* B = kpT + (long)h * NFP * N_SEQ + kc * 256;
  const int wbase = tid & 192;

  const unsigned short* asrc[2];
  #pragma unroll
  for (int e = 0; e < 2; ++e) {
    int chunk = e * 256 + tid;
    int r = chunk >> 3, c = chunk & 7;
    asrc[e] = A + (long)r * N_SEQ + (c ^ (r & 7)) * 8;
  }
  const unsigned short* bsrc[10];
  #pragma unroll
  for (int e = 0; e < 10; ++e) {
    int chunk = e * 256 + tid;
    int r = chunk >> 3, c = chunk & 7;
    bsrc[e] = B + (long)r * N_SEQ + (c ^ (r & 7)) * 8;
  }

  f32x4 acc[2][10] = {};

  for (int k0 = 0; k0 < 256; k0 += 64) {
    #pragma unroll
    for (int e = 0; e < 2; ++e) g2l16(asrc[e] + k0, a_s4 + e * 256 + wbase);
    #pragma unroll
    for (int e = 0; e < 10; ++e) g2l16(bsrc[e] + k0, b_s4 + e * 256 + wbase);
    __syncthreads();
    #pragma unroll
    for (int ks = 0; ks < 2; ++ks) {
      bf16x8 af[2], bv[10];
      #pragma unroll
      for (int i = 0; i < 2; ++i) {
        int r = wr * 32 + i * 16 + lr;
        af[i] = *(const bf16x8*)&a_s4[r * 8 + ((ks * 4 + lg) ^ (r & 7))];
      }
      #pragma unroll
      for (int j = 0; j < 10; ++j) {
        int r = wc * 160 + j * 16 + lr;
        bv[j] = *(const bf16x8*)&b_s4[r * 8 + ((ks * 4 + lg) ^ (r & 7))];
      }
      #pragma unroll
      for (int i = 0; i < 2; ++i)
        #pragma unroll
        for (int j = 0; j < 10; ++j)
          acc[i][j] = __builtin_amdgcn_mfma_f32_16x16x32_bf16(af[i], bv[j], acc[i][j], 0, 0, 0);
    }
    __syncthreads();
  }

  float* pbase = part + ((long)(h * 32 + kc)) * 64 * NFP;
  #pragma unroll
  for (int i = 0; i < 2; ++i) {
    #pragma unroll
    for (int j = 0; j < 10; ++j) {
      int gn = wc * 160 + j * 16 + lr;
      #pragma unroll
      for (int rg = 0; rg < 4; ++rg) {
        int gm = wr * 32 + i * 16 + lg * 4 + rg;
        pbase[(long)gm * NFP + gn] = acc[i][j][rg];
      }
    }
  }
}

// ctxpad[h][96][320]: rows 0-63 = sum of part, row 64 = ksum, rows 65-95 = 0.
__global__ void ctx_reduce_kernel(const float* __restrict__ part,
                                  const float* __restrict__ ksum,
                                  unsigned short* __restrict__ ctxpad) {
  int i = blockIdx.x * 256 + threadIdx.x;  // < 8*96*320 = 245760
  int h = i / (96 * NFP);
  int rem = i % (96 * NFP);
  int r = rem / NFP, j = rem % NFP;
  float s = 0.f;
  if (r < 64) {
    #pragma unroll 4
    for (int kc = 0; kc < 32; ++kc)
      s += part[((long)(h * 32 + kc)) * 64 * NFP + r * NFP + j];
  } else if (r == 64) {
    s = ksum[h * NFP + j];
  }
  ctxpad[i] = f2bf(s);
}

// -------------------- launch --------------------

extern "C" void kernel_launch(void* const* d_in, const int* in_sizes, int n_in,
                              void* d_out, int out_size, void* d_ws, size_t ws_size,
                              hipStream_t stream) {
  const float* x    = (const float*)d_in[0];
  const float* proj = (const float*)d_in[1];
  const float* ln1g = (const float*)d_in[2];
  const float* ln1b = (const float*)d_in[3];
  const float* wq   = (const float*)d_in[4];
  const float* wk   = (const float*)d_in[5];
  const float* wv   = (const float*)d_in[6];
  const float* wo   = (const float*)d_in[7];
  const float* wob  = (const float*)d_in[8];
  const float* ln2g = (const float*)d_in[9];
  const float* ln2b = (const float*)d_in[10];
  const float* w1   = (const float*)d_in[11];
  const float* b1   = (const float*)d_in[12];
  const float* w2   = (const float*)d_in[13];
  const float* b2   = (const float*)d_in[14];

  char* ws = (char*)d_ws;
  unsigned short* wtqkv = (unsigned short*)(ws + 0);
  unsigned short* wot   = (unsigned short*)(ws + 1572864);
  unsigned short* w1t   = (unsigned short*)(ws + 2097152);
  unsigned short* w2t   = (unsigned short*)(ws + 4194304);
  unsigned short* pb    = (unsigned short*)(ws + 6291456);
  unsigned short* h_bf  = (unsigned short*)(ws + 6332416);
  unsigned short* qkv   = (unsigned short*)(ws + 14721024);
  float* diag           = (float*)(ws + 39886848);
  unsigned short* qp    = (unsigned short*)(ws + 40411136);
  unsigned short* kpT   = (unsigned short*)(ws + 82354176);
  unsigned* mk          = (unsigned*)(ws + 124297216);
  unsigned short* vT    = (unsigned short*)(ws + 124297472);
  float* part           = (float*)(ws + 132686080);
  float* ksum           = (float*)(ws + 153657600);
  unsigned short* ctxpad= (unsigned short*)(ws + 153667840);
  unsigned short* gbf   = (unsigned short*)(ws + 130468096);
  unsigned short* attn  = h_bf;  // reuse (h_bf dead after QKV GEMM)
  unsigned short* h2    = qkv;   // reuse (qkv dead after phi/vtrans)
  float* xb             = (float*)d_out;

  dim3 blk(256);

  transpose_w_kernel<<<dim3(16, 16), dim3(32, 8), 0, stream>>>(wq, wtqkv, 512, 512);
  transpose_w_kernel<<<dim3(16, 16), dim3(32, 8), 0, stream>>>(wk, wtqkv + 262144, 512, 512);
  transpose_w_kernel<<<dim3(16, 16), dim3(32, 8), 0, stream>>>(wv, wtqkv + 524288, 512, 512);
  transpose_w_kernel<<<dim3(16, 16), dim3(32, 8), 0, stream>>>(wo, wot, 512, 512);
  transpose_w_kernel<<<dim3(64, 16), dim3(32, 8), 0, stream>>>(w1, w1t, 512, 2048);
  transpose_w_kernel<<<dim3(16, 64), dim3(32, 8), 0, stream>>>(w2, w2t, 2048, 512);
  projb_kernel<<<80, blk, 0, stream>>>(proj, pb);
  init_mk_kernel<<<1, 64, 0, stream>>>(mk);

  ln_kernel<<<N_SEQ, blk, 0, stream>>>(x, ln1g, ln1b, h_bf);

  // QKV: one GEMM, C = qkv [8192][1536]
  gemm256_kernel<256, 256, EPI_BF16><<<dim3(32, 6), dim3(512), 0, stream>>>(
      h_bf, 512, wtqkv, 512, qkv, DQKV, 512, nullptr, nullptr, 0);

  diag_kernel<<<512, blk, 0, stream>>>(qkv, diag);
  vtrans_kernel<<<dim3(1, 128, 8), blk, 0, stream>>>(qkv + 1024, vT);

  phi_kernel<0><<<dim3(128, 1, 8), blk, 0, stream>>>(qkv, pb, qp, diag, mk);
  phi_kernel<1><<<dim3(128, 1, 8), blk, 0, stream>>>(qkv + 512, pb, kpT, diag + 65536, mk);
  phi_kernel<2><<<dim3(128, 1, 8), blk, 0, stream>>>(qkv + 512, pb, kpT, diag + 65536, mk);

  ksum_kernel<<<dim3(80, 8), blk, 0, stream>>>(kpT, ksum);
  ctx_mfma_kernel<<<dim3(32, 8), blk, 0, stream>>>(vT, kpT, part);
  ctx_reduce_kernel<<<960, blk, 0, stream>>>(part, ksum, ctxpad);

  gemm_kernel<128, 96, 32, 96, EPI_CTX><<<dim3(64, 1, 8), blk, 0, stream>>>(
      qp, NFP, (long)N_SEQ * NFP, ctxpad, NFP, 96 * NFP, attn, 512, 64, NFP,
      nullptr, nullptr, 0);

  gemm_kernel<128, 128, 64, 64, EPI_BIAS_RES_F32><<<dim3(64, 4, 1), blk, 0, stream>>>(
      attn, 512, 0, wot, 512, 0, xb, 512, 0, 512,
      wob, x, 512);

  ln_kernel<<<N_SEQ, blk, 0, stream>>>(xb, ln2g, ln2b, h2);

  gemm256_kernel<256, 256, EPI_BIAS_GELU><<<dim3(32, 8), dim3(512), 0, stream>>>(
      h2, 512, w1t, 512, gbf, 2048, 512, b1, nullptr, 0);

  gemm256_kernel<256, 128, EPI_BIAS_RES_F32><<<dim3(32, 4), dim3(512), 0, stream>>>(
      gbf, 2048, w2t, 2048, d_out, 512, 2048, b2, xb, 512);
}

// Round 5
// 234.828 us; speedup vs baseline: 1.1141x; 1.1141x over previous
//
#include <hip/hip_runtime.h>
#include <math.h>

// ---------------------------------------------------------------------------
// Performer encoder layer, MI355X round-5: double-buffered 128-tile GEMMs with
// 2-3 blocks/CU (cross-block overlap hides the per-tile drain), diag fused
// into phi, ksum fused into phi<2> as block partials.
// N=8192, D=512, H=8, DH=64, NF=266 (padded to NFP=320 = 5*64).
// Workspace layout (bytes):
//   0         wtqkv  bf16 [1536][512]  (wq^T,wk^T,wv^T stacked)
//   1572864   wot    bf16 [512][512]
//   2097152   w1t    bf16 [2048][512]
//   4194304   w2t    bf16 [512][2048]
//   6291456   projb  bf16 [320][64]
//   6332416   h_bf   bf16 [8192][512]     (reused as attn_bf)
//   14721024  qkv    bf16 [8192][1536]  q=cols 0-511, k=512-1023, v=1024-1535
//                                        (reused as h2_bf)
//   40411136  qp     bf16 [8][8192][320]
//   82354176  kpT    bf16 [8][320][8192]
//   124297216 mk     u32  [8]
//   124297472 vT     bf16 [8][64][8192]
//   132686080 part   f32  [8][32][64][320]   (ctx split-K partials)
//   153657600 kspart f32  [8][128][320]      (ksum block partials)
//   154968320 ksum   f32  [8][320]
//   154978560 ctxpad bf16 [8][96][320]   (rows 0-63 ctx^T, row 64 ksum, 65+ 0)
//   130468096 gbf    bf16 [8192][2048]   (overlaps vT/part/kspart/ksum/ctxpad;
//                                         lifetimes disjoint: all dead pre-FFN1)
//   total 164022528 B.  xb (f32 [8192][512]) lives in d_out.
// ---------------------------------------------------------------------------

typedef __attribute__((ext_vector_type(8))) short bf16x8;
typedef __attribute__((ext_vector_type(4))) float f32x4;

#define N_SEQ 8192
#define DMODEL 512
#define DQKV 1536
#define NHEAD 8
#define DHEAD 64
#define NF 266
#define NFP 320
#define PEPS 1e-4f
#define LNEPS 1e-5f
#define DNORM 0.35355339059327373f
#define RATIO 0.06131393694f

__device__ __forceinline__ unsigned short f2bf(float f) {
  unsigned u = __float_as_uint(f);
  u += 0x7FFFu + ((u >> 16) & 1u);
  return (unsigned short)(u >> 16);
}
__device__ __forceinline__ float bf2f(unsigned short b) {
  return __uint_as_float(((unsigned)b) << 16);
}
__device__ __forceinline__ unsigned enc_f32(float f) {
  unsigned i = __float_as_uint(f);
  return (i & 0x80000000u) ? ~i : (i | 0x80000000u);
}
__device__ __forceinline__ float dec_f32(unsigned u) {
  return (u & 0x80000000u) ? __uint_as_float(u & 0x7FFFFFFFu) : __uint_as_float(~u);
}

// async global->LDS, 16B per lane. LDS dest must be wave-uniform base; HW adds
// lane*16. Global source is per-lane (pre-swizzled by caller).
__device__ __forceinline__ void g2l16(const void* g, void* l) {
  __builtin_amdgcn_global_load_lds(
      (const __attribute__((address_space(1))) void*)g,
      (__attribute__((address_space(3))) void*)l, 16, 0, 0);
}

// -------------------- small prep kernels --------------------

__global__ void init_mk_kernel(unsigned* mk) {
  if (threadIdx.x < NHEAD) mk[threadIdx.x] = 0x007FFFFFu;  // enc(-inf)
}

// dst[c][r] = bf16(src[r][c]); src is [R][C] f32. grid (C/32, R/32), block (32,8)
__global__ __launch_bounds__(256) void transpose_w_kernel(const float* __restrict__ src,
                                                          unsigned short* __restrict__ dst,
                                                          int R, int C) {
  __shared__ float tile[32][33];
  int c0 = blockIdx.x * 32, r0 = blockIdx.y * 32;
  int tx = threadIdx.x, ty = threadIdx.y;
  #pragma unroll
  for (int i = ty; i < 32; i += 8)
    tile[i][tx] = src[(long)(r0 + i) * C + c0 + tx];
  __syncthreads();
  #pragma unroll
  for (int i = ty; i < 32; i += 8)
    dst[(long)(c0 + i) * R + r0 + tx] = f2bf(tile[tx][i]);
}

__global__ void projb_kernel(const float* __restrict__ proj, unsigned short* __restrict__ pb) {
  int id = blockIdx.x * 256 + threadIdx.x;  // < 320*64
  int j = id >> 6;
  pb[id] = (j < NF) ? f2bf(proj[(long)j * 64 + (id & 63)] * DNORM) : (unsigned short)0;
}

// v slice of qkv [8192][1536] -> vT [8][64][8192].  grid (1,128,8), block 256.
__global__ __launch_bounds__(256) void vtrans_kernel(const unsigned short* __restrict__ v,
                                                     unsigned short* __restrict__ vT) {
  __shared__ unsigned short tl[64][66];
  int h = blockIdx.z, n0 = blockIdx.y * 64;
  int tid = threadIdx.x;
  int i = tid >> 2, c0 = (tid & 3) * 16;
  const unsigned short* src = v + (long)(n0 + i) * DQKV + h * DHEAD + c0;
  uint4 u0 = *(const uint4*)src;
  uint4 u1 = *(const uint4*)(src + 8);
  const unsigned short* e0 = (const unsigned short*)&u0;
  const unsigned short* e1 = (const unsigned short*)&u1;
  #pragma unroll
  for (int k = 0; k < 8; ++k) { tl[i][c0 + k] = e0[k]; tl[i][c0 + 8 + k] = e1[k]; }
  __syncthreads();
  unsigned short tmp[16];
  #pragma unroll
  for (int k = 0; k < 16; ++k) tmp[k] = tl[c0 + k][i];
  unsigned short* dst = vT + ((long)h * DHEAD + i) * N_SEQ + n0 + c0;
  *(uint4*)dst = *(uint4*)&tmp[0];
  *(uint4*)(dst + 8) = *(uint4*)&tmp[8];
}

// -------------------- layernorm --------------------

__global__ __launch_bounds__(256) void ln_kernel(const float* __restrict__ x,
                                                 const float* __restrict__ g,
                                                 const float* __restrict__ b,
                                                 unsigned short* __restrict__ out) {
  __shared__ float sred[4];
  int row = blockIdx.x, t = threadIdx.x;
  float2 v = ((const float2*)(x + (long)row * DMODEL))[t];
  float s = v.x + v.y;
  #pragma unroll
  for (int m = 32; m >= 1; m >>= 1) s += __shfl_xor(s, m);
  if ((t & 63) == 0) sred[t >> 6] = s;
  __syncthreads();
  float mu = (sred[0] + sred[1] + sred[2] + sred[3]) * (1.0f / DMODEL);
  __syncthreads();
  float d0 = v.x - mu, d1 = v.y - mu;
  float q = d0 * d0 + d1 * d1;
  #pragma unroll
  for (int m = 32; m >= 1; m >>= 1) q += __shfl_xor(q, m);
  if ((t & 63) == 0) sred[t >> 6] = q;
  __syncthreads();
  float var = (sred[0] + sred[1] + sred[2] + sred[3]) * (1.0f / DMODEL);
  float inv = rsqrtf(var + LNEPS);
  int c = t * 2;
  unsigned short o0 = f2bf(d0 * inv * g[c] + b[c]);
  unsigned short o1 = f2bf(d1 * inv * g[c + 1] + b[c + 1]);
  ((unsigned*)(out + (long)row * DMODEL))[t] = ((unsigned)o1 << 16) | o0;
}

enum { EPI_BF16 = 0, EPI_CTX = 1, EPI_BIAS_RES_F32 = 2, EPI_BIAS_GELU = 3 };

// -------------------- double-buffered 128-tile 4-wave GEMM --------------------
// C[M,N] = A[M,K] x Bt[N,K]^T, fp32 acc. 256 threads. BK=64.
// T3-minimum pipeline: stage(next K-tile) -> compute(cur) -> barrier (drain).
// Loads for tile t+1 stay in flight during compute of tile t; co-resident
// blocks (2-3/CU via <=64KB LDS) overlap each other's drain stalls.
// EPI_CTX: Bt has 96 rows (64 ctx + ksum row at 64 + zeros); epilogue divides
// cols 0..63 by the col-64 dot product (d = qp . ksum), broadcast via shfl.

template <int BM, int BN, int WM, int WN, int EPI>
__global__ __launch_bounds__(256) void gemm_kernel(
    const unsigned short* __restrict__ A, int lda, long sA,
    const unsigned short* __restrict__ Bt, int ldb, long sB,
    void* __restrict__ Cv, int ldc, long sC,
    int K,
    const float* __restrict__ bias,
    const float* __restrict__ res, int ldr) {
  static_assert((BM / WM) * (BN / WN) == 4, "need 4 waves");
  constexpr int MR = WM / 16, NR = WN / 16;
  constexpr int WNN = BN / WN;
  constexpr int AIT = BM * 8 / 256;
  constexpr int BIT = BN * 8 / 256;
  const int tid = threadIdx.x;
  const int wave = tid >> 6, lane = tid & 63;
  const int lr = lane & 15, lg = lane >> 4;
  const int wr = wave / WNN, wc = wave % WNN;
  const int m0 = blockIdx.x * BM, n0 = blockIdx.y * BN;
  const int z = blockIdx.z;
  A += (long)z * sA;
  Bt += (long)z * sB;

  __shared__ uint4 a_s[2][BM * 8];
  __shared__ uint4 b_s[2][BN * 8];

  const unsigned short* asrc[AIT];
  #pragma unroll
  for (int e = 0; e < AIT; ++e) {
    int chunk = e * 256 + tid;
    int r = chunk >> 3, c = chunk & 7;
    asrc[e] = A + (long)(m0 + r) * lda + (c ^ (r & 7)) * 8;
  }
  const unsigned short* bsrc[BIT];
  #pragma unroll
  for (int e = 0; e < BIT; ++e) {
    int chunk = e * 256 + tid;
    int r = chunk >> 3, c = chunk & 7;
    bsrc[e] = Bt + (long)(n0 + r) * ldb + (c ^ (r & 7)) * 8;
  }
  const int wbase = tid & 192;

  f32x4 acc[MR][NR] = {};

  auto stage = [&](int buf, int t) {
    #pragma unroll
    for (int e = 0; e < AIT; ++e)
      g2l16(asrc[e] + t * 64, &a_s[buf][e * 256 + wbase]);
    #pragma unroll
    for (int e = 0; e < BIT; ++e)
      g2l16(bsrc[e] + t * 64, &b_s[buf][e * 256 + wbase]);
  };
  auto compute = [&](int buf) {
    #pragma unroll
    for (int ks = 0; ks < 2; ++ks) {
      bf16x8 af[MR], bv[NR];
      #pragma unroll
      for (int i = 0; i < MR; ++i) {
        int r = wr * WM + i * 16 + lr;
        af[i] = *(const bf16x8*)&a_s[buf][r * 8 + ((ks * 4 + lg) ^ (r & 7))];
      }
      #pragma unroll
      for (int j = 0; j < NR; ++j) {
        int r = wc * WN + j * 16 + lr;
        bv[j] = *(const bf16x8*)&b_s[buf][r * 8 + ((ks * 4 + lg) ^ (r & 7))];
      }
      #pragma unroll
      for (int i = 0; i < MR; ++i)
        #pragma unroll
        for (int j = 0; j < NR; ++j)
          acc[i][j] = __builtin_amdgcn_mfma_f32_16x16x32_bf16(af[i], bv[j], acc[i][j], 0, 0, 0);
    }
  };

  const int NT = K >> 6;
  stage(0, 0);
  __syncthreads();
  int cur = 0;
  for (int t = 0; t < NT - 1; ++t) {
    stage(cur ^ 1, t + 1);
    compute(cur);
    __syncthreads();
    cur ^= 1;
  }
  compute(cur);

  if constexpr (EPI == EPI_CTX) {
    #pragma unroll
    for (int i = 0; i < MR; ++i) {
      #pragma unroll
      for (int rg = 0; rg < 4; ++rg) {
        float dv = __shfl(acc[i][4][rg], lane & 48);  // col 64 (lr==0 lane)
        float inv = 1.0f / dv;
        int gm = m0 + wr * WM + i * 16 + lg * 4 + rg;
        #pragma unroll
        for (int j = 0; j < 4; ++j) {
          int gn = j * 16 + lr;  // cols 0..63
          ((unsigned short*)Cv)[(long)z * sC + (long)gm * ldc + gn] =
              f2bf(acc[i][j][rg] * inv);
        }
      }
    }
    return;
  }

  #pragma unroll
  for (int i = 0; i < MR; ++i) {
    #pragma unroll
    for (int j = 0; j < NR; ++j) {
      int gn = n0 + wc * WN + j * 16 + lr;
      #pragma unroll
      for (int rg = 0; rg < 4; ++rg) {
        int gm = m0 + wr * WM + i * 16 + lg * 4 + rg;
        float v = acc[i][j][rg];
        if (EPI == EPI_BF16) {
          ((unsigned short*)Cv)[(long)z * sC + (long)gm * ldc + gn] = f2bf(v);
        } else if (EPI == EPI_BIAS_RES_F32) {
          v += bias[gn] + res[(long)gm * ldr + gn];
          ((float*)Cv)[(long)z * sC + (long)gm * ldc + gn] = v;
        } else if (EPI == EPI_BIAS_GELU) {
          v += bias[gn];
          float t3 = 0.7978845608028654f * (v + 0.044715f * v * v * v);
          v = v / (1.0f + __expf(-2.0f * t3));  // 0.5v(1+tanh(t3))
          ((unsigned short*)Cv)[(long)z * sC + (long)gm * ldc + gn] = f2bf(v);
        }
      }
    }
  }
}

// -------------------- phi: dd GEMM + epilogue --------------------
// diag = 0.5*dnorm^2*|row|^2 computed in-kernel from the staged A-tile.
// MODE 0: q -> qp row-major [h][n][NFP] (per-row max).
// MODE 1: k max pass (atomicMax enc).
// MODE 2: k exp pass -> kpT [h][NFP][N] (LDS transpose) + ksum block partials.

template <int MODE>
__global__ __launch_bounds__(256) void phi_kernel(
    const unsigned short* __restrict__ QK,  // [8192][1536] slice (q or k cols)
    const unsigned short* __restrict__ pb,  // [320][64]
    unsigned short* __restrict__ out,       // qp or kpT
    unsigned* __restrict__ mk,
    float* __restrict__ kspart) {           // [8][128][320] (MODE 2)
  const int tid = threadIdx.x;
  const int wave = tid >> 6, lane = tid & 63;
  const int lr = lane & 15, lg = lane >> 4;
  const int h = blockIdx.z;
  const int m0 = blockIdx.x * 64;

  __shared__ uint4 smem[3072];       // a(512) + b(2560); reused as kt32 in MODE 2
  __shared__ float sred[4];
  __shared__ float kls[4 * NFP];     // per-wave colsum partials (MODE 2)
  uint4* a_s4 = smem;
  uint4* b_s4 = smem + 512;

  const unsigned short* Aq = QK + (long)m0 * DQKV + h * DHEAD;
  const int wbase = tid & 192;

  #pragma unroll
  for (int e = 0; e < 2; ++e) {
    int chunk = e * 256 + tid;
    int r = chunk >> 3, c = chunk & 7;
    g2l16(Aq + (long)r * DQKV + (c ^ (r & 7)) * 8, a_s4 + e * 256 + wbase);
  }
  #pragma unroll
  for (int e = 0; e < 10; ++e) {
    int chunk = e * 256 + tid;
    int r = chunk >> 3, c = chunk & 7;
    g2l16(pb + (long)r * DHEAD + (c ^ (r & 7)) * 8, b_s4 + e * 256 + wbase);
  }
  __syncthreads();

  f32x4 acc[20] = {};
  float qs = 0.f;
  #pragma unroll
  for (int ks = 0; ks < 2; ++ks) {
    int rA = wave * 16 + lr;
    bf16x8 af = *(const bf16x8*)&a_s4[rA * 8 + ((ks * 4 + lg) ^ (rA & 7))];
    if (MODE != 1) {
      #pragma unroll
      for (int i = 0; i < 8; ++i) {
        float f = bf2f((unsigned short)af[i]);
        qs += f * f;
      }
    }
    #pragma unroll
    for (int j = 0; j < 20; ++j) {
      int rB = j * 16 + lr;
      bf16x8 bv = *(const bf16x8*)&b_s4[rB * 8 + ((ks * 4 + lg) ^ (rB & 7))];
      acc[j] = __builtin_amdgcn_mfma_f32_16x16x32_bf16(af, bv, acc[j], 0, 0, 0);
    }
  }

  const int gmb = m0 + wave * 16 + lg * 4;  // + rg

  if (MODE == 1) {
    float m = -3.0e38f;
    #pragma unroll
    for (int j = 0; j < 17; ++j) {
      bool valid = (j < 16) || (lr < 10);  // col = j*16+lr < 266
      if (valid) {
        #pragma unroll
        for (int rg = 0; rg < 4; ++rg) m = fmaxf(m, acc[j][rg]);
      }
    }
    #pragma unroll
    for (int s = 1; s < 64; s <<= 1) m = fmaxf(m, __shfl_xor(m, s));
    if (lane == 0) sred[wave] = m;
    __syncthreads();
    if (tid == 0) {
      float mm = fmaxf(fmaxf(sred[0], sred[1]), fmaxf(sred[2], sred[3]));
      atomicMax(&mk[h], enc_f32(mm));
    }
    return;
  }

  // row |.|^2: reduce qs over lg (row id = wave*16+lr), then map to C rows
  qs += __shfl_xor(qs, 16);
  qs += __shfl_xor(qs, 32);
  float dg[4];
  #pragma unroll
  for (int rg = 0; rg < 4; ++rg) dg[rg] = 0.0625f * __shfl(qs, lg * 4 + rg);

  if (MODE == 0) {
    float mrow[4];
    #pragma unroll
    for (int rg = 0; rg < 4; ++rg) mrow[rg] = -3.0e38f;
    #pragma unroll
    for (int j = 0; j < 17; ++j) {
      bool valid = (j < 16) || (lr < 10);
      if (valid) {
        #pragma unroll
        for (int rg = 0; rg < 4; ++rg) mrow[rg] = fmaxf(mrow[rg], acc[j][rg]);
      }
    }
    #pragma unroll
    for (int s = 1; s < 16; s <<= 1)
      #pragma unroll
      for (int rg = 0; rg < 4; ++rg) mrow[rg] = fmaxf(mrow[rg], __shfl_xor(mrow[rg], s));

    #pragma unroll
    for (int j = 0; j < 20; ++j) {
      int col = j * 16 + lr;
      #pragma unroll
      for (int rg = 0; rg < 4; ++rg) {
        float v = 0.f;
        if (col < NF) v = RATIO * (__expf(acc[j][rg] - dg[rg] - mrow[rg]) + PEPS);
        out[((long)h * N_SEQ + gmb + rg) * NFP + col] = f2bf(v);
      }
    }
  } else {
    // MODE 2: exp with global max; transposed write kpT[h][col][n]; colsums.
    float mh = dec_f32(mk[h]);
    unsigned* kt32 = (unsigned*)smem;  // [320][33] uints (pairs of bf16 along n)
    __syncthreads();                   // a_s4/b_s4 reads done
    #pragma unroll
    for (int j = 0; j < 20; ++j) {
      int col = j * 16 + lr;
      float scol = 0.f;
      #pragma unroll
      for (int p = 0; p < 2; ++p) {
        float v0 = 0.f, v1 = 0.f;
        if (col < NF) {
          v0 = RATIO * (__expf(acc[j][2 * p] - dg[2 * p] - mh) + PEPS);
          v1 = RATIO * (__expf(acc[j][2 * p + 1] - dg[2 * p + 1] - mh) + PEPS);
        }
        scol += v0 + v1;
        kt32[col * 33 + wave * 8 + lg * 2 + p] =
            (unsigned)f2bf(v0) | ((unsigned)f2bf(v1) << 16);
      }
      // colsum over the wave's 16 rows (reduce over lg)
      scol += __shfl_xor(scol, 16);
      scol += __shfl_xor(scol, 32);
      if (lg == 0) kls[wave * NFP + col] = scol;
    }
    __syncthreads();
    #pragma unroll
    for (int it = 0; it < 10; ++it) {
      int r = it * 32 + (tid >> 3);
      int cu = (tid & 7) * 4;
      uint4 o;
      o.x = kt32[r * 33 + cu + 0];
      o.y = kt32[r * 33 + cu + 1];
      o.z = kt32[r * 33 + cu + 2];
      o.w = kt32[r * 33 + cu + 3];
      *(uint4*)(out + ((long)h * NFP + r) * N_SEQ + m0 + cu * 2) = o;
    }
    #pragma unroll
    for (int c0 = tid; c0 < NFP; c0 += 256) {
      float s = kls[c0] + kls[NFP + c0] + kls[2 * NFP + c0] + kls[3 * NFP + c0];
      kspart[((long)h * 128 + blockIdx.x) * NFP + c0] = s;
    }
  }
}

// -------------------- ksum reduce: [8][320] from 128 block partials ---------

__global__ void ksum_red_kernel(const float* __restrict__ kspart,
                                float* __restrict__ ksum) {
  int i = blockIdx.x * 256 + threadIdx.x;
  if (i >= NHEAD * NFP) return;
  float s = 0.f;
  #pragma unroll 4
  for (int b = 0; b < 128; ++b) s += kspart[(long)(i / NFP) * 128 * NFP + (long)b * NFP + i % NFP];
  ksum[i] = s;
}

// -------------------- ctx split-K MFMA: part[h][kc] = vT chunk x kpT chunk ----

__global__ __launch_bounds__(256) void ctx_mfma_kernel(
    const unsigned short* __restrict__ vT,   // [8][64][8192]
    const unsigned short* __restrict__ kpT,  // [8][320][8192]
    float* __restrict__ part) {              // [8][32][64][320]
  const int tid = threadIdx.x;
  const int wave = tid >> 6, lane = tid & 63;
  const int lr = lane & 15, lg = lane >> 4;
  const int wr = wave >> 1, wc = wave & 1;  // WM=32, WN=160
  const int kc = blockIdx.x, h = blockIdx.y;

  __shared__ uint4 a_s4[64 * 8];
  __shared__ uint4 b_s4[NFP * 8];

  const unsigned short* A = vT + (long)h * DHEAD * N_SEQ + kc * 256;
  const unsigned short* B = kpT + (long)h * NFP * N_SEQ + kc * 256;
  const int wbase = tid & 192;

  const unsigned short* asrc[2];
  #pragma unroll
  for (int e = 0; e < 2; ++e) {
    int chunk = e * 256 + tid;
    int r = chunk >> 3, c = chunk & 7;
    asrc[e] = A + (long)r * N_SEQ + (c ^ (r & 7)) * 8;
  }
  const unsigned short* bsrc[10];
  #pragma unroll
  for (int e = 0; e < 10; ++e) {
    int chunk = e * 256 + tid;
    int r = chunk >> 3, c = chunk & 7;
    bsrc[e] = B + (long)r * N_SEQ + (c ^ (r & 7)) * 8;
  }

  f32x4 acc[2][10] = {};

  for (int k0 = 0; k0 < 256; k0 += 64) {
    #pragma unroll
    for (int e = 0; e < 2; ++e) g2l16(asrc[e] + k0, a_s4 + e * 256 + wbase);
    #pragma unroll
    for (int e = 0; e < 10; ++e) g2l16(bsrc[e] + k0, b_s4 + e * 256 + wbase);
    __syncthreads();
    #pragma unroll
    for (int ks = 0; ks < 2; ++ks) {
      bf16x8 af[2], bv[10];
      #pragma unroll
      for (int i = 0; i < 2; ++i) {
        int r = wr * 32 + i * 16 + lr;
        af[i] = *(const bf16x8*)&a_s4[r * 8 + ((ks * 4 + lg) ^ (r & 7))];
      }
      #pragma unroll
      for (int j = 0; j < 10; ++j) {
        int r = wc * 160 + j * 16 + lr;
        bv[j] = *(const bf16x8*)&b_s4[r * 8 + ((ks * 4 + lg) ^ (r & 7))];
      }
      #pragma unroll
      for (int i = 0; i < 2; ++i)
        #pragma unroll
        for (int j = 0; j < 10; ++j)
          acc[i][j] = __builtin_amdgcn_mfma_f32_16x16x32_bf16(af[i], bv[j], acc[i][j], 0, 0, 0);
    }
    __syncthreads();
  }

  float* pbase = part + ((long)(h * 32 + kc)) * 64 * NFP;
  #pragma unroll
  for (int i = 0; i < 2; ++i) {
    #pragma unroll
    for (int j = 0; j < 10; ++j) {
      int gn = wc * 160 + j * 16 + lr;
      #pragma unroll
      for (int rg = 0; rg < 4; ++rg) {
        int gm = wr * 32 + i * 16 + lg * 4 + rg;
        pbase[(long)gm * NFP + gn] = acc[i][j][rg];
      }
    }
  }
}

// ctxpad[h][96][320]: rows 0-63 = sum of part, row 64 = ksum, rows 65-95 = 0.
__global__ void ctx_reduce_kernel(const float* __restrict__ part,
                                  const float* __restrict__ ksum,
                                  unsigned short* __restrict__ ctxpad) {
  int i = blockIdx.x * 256 + threadIdx.x;  // < 8*96*320 = 245760
  int h = i / (96 * NFP);
  int rem = i % (96 * NFP);
  int r = rem / NFP, j = rem % NFP;
  float s = 0.f;
  if (r < 64) {
    #pragma unroll 4
    for (int kc = 0; kc < 32; ++kc)
      s += part[((long)(h * 32 + kc)) * 64 * NFP + r * NFP + j];
  } else if (r == 64) {
    s = ksum[h * NFP + j];
  }
  ctxpad[i] = f2bf(s);
}

// -------------------- launch --------------------

extern "C" void kernel_launch(void* const* d_in, const int* in_sizes, int n_in,
                              void* d_out, int out_size, void* d_ws, size_t ws_size,
                              hipStream_t stream) {
  const float* x    = (const float*)d_in[0];
  const float* proj = (const float*)d_in[1];
  const float* ln1g = (const float*)d_in[2];
  const float* ln1b = (const float*)d_in[3];
  const float* wq   = (const float*)d_in[4];
  const float* wk   = (const float*)d_in[5];
  const float* wv   = (const float*)d_in[6];
  const float* wo   = (const float*)d_in[7];
  const float* wob  = (const float*)d_in[8];
  const float* ln2g = (const float*)d_in[9];
  const float* ln2b = (const float*)d_in[10];
  const float* w1   = (const float*)d_in[11];
  const float* b1   = (const float*)d_in[12];
  const float* w2   = (const float*)d_in[13];
  const float* b2   = (const float*)d_in[14];

  char* ws = (char*)d_ws;
  unsigned short* wtqkv = (unsigned short*)(ws + 0);
  unsigned short* wot   = (unsigned short*)(ws + 1572864);
  unsigned short* w1t   = (unsigned short*)(ws + 2097152);
  unsigned short* w2t   = (unsigned short*)(ws + 4194304);
  unsigned short* pb    = (unsigned short*)(ws + 6291456);
  unsigned short* h_bf  = (unsigned short*)(ws + 6332416);
  unsigned short* qkv   = (unsigned short*)(ws + 14721024);
  unsigned short* qp    = (unsigned short*)(ws + 40411136);
  unsigned short* kpT   = (unsigned short*)(ws + 82354176);
  unsigned* mk          = (unsigned*)(ws + 124297216);
  unsigned short* vT    = (unsigned short*)(ws + 124297472);
  float* part           = (float*)(ws + 132686080);
  float* kspart         = (float*)(ws + 153657600);
  float* ksum           = (float*)(ws + 154968320);
  unsigned short* ctxpad= (unsigned short*)(ws + 154978560);
  unsigned short* gbf   = (unsigned short*)(ws + 130468096);
  unsigned short* attn  = h_bf;  // reuse (h_bf dead after QKV GEMM)
  unsigned short* h2    = qkv;   // reuse (qkv dead after phi/vtrans)
  float* xb             = (float*)d_out;

  dim3 blk(256);

  transpose_w_kernel<<<dim3(16, 16), dim3(32, 8), 0, stream>>>(wq, wtqkv, 512, 512);
  transpose_w_kernel<<<dim3(16, 16), dim3(32, 8), 0, stream>>>(wk, wtqkv + 262144, 512, 512);
  transpose_w_kernel<<<dim3(16, 16), dim3(32, 8), 0, stream>>>(wv, wtqkv + 524288, 512, 512);
  transpose_w_kernel<<<dim3(16, 16), dim3(32, 8), 0, stream>>>(wo, wot, 512, 512);
  transpose_w_kernel<<<dim3(64, 16), dim3(32, 8), 0, stream>>>(w1, w1t, 512, 2048);
  transpose_w_kernel<<<dim3(16, 64), dim3(32, 8), 0, stream>>>(w2, w2t, 2048, 512);
  projb_kernel<<<80, blk, 0, stream>>>(proj, pb);
  init_mk_kernel<<<1, 64, 0, stream>>>(mk);

  ln_kernel<<<N_SEQ, blk, 0, stream>>>(x, ln1g, ln1b, h_bf);

  // QKV: one GEMM, C = qkv [8192][1536]  (768 blocks, 2/CU resident)
  gemm_kernel<128, 128, 64, 64, EPI_BF16><<<dim3(64, 12, 1), blk, 0, stream>>>(
      h_bf, 512, 0, wtqkv, 512, 0, qkv, DQKV, 0, 512, nullptr, nullptr, 0);

  vtrans_kernel<<<dim3(1, 128, 8), blk, 0, stream>>>(qkv + 1024, vT);

  phi_kernel<0><<<dim3(128, 1, 8), blk, 0, stream>>>(qkv, pb, qp, mk, nullptr);
  phi_kernel<1><<<dim3(128, 1, 8), blk, 0, stream>>>(qkv + 512, pb, kpT, mk, nullptr);
  phi_kernel<2><<<dim3(128, 1, 8), blk, 0, stream>>>(qkv + 512, pb, kpT, mk, kspart);

  ksum_red_kernel<<<10, blk, 0, stream>>>(kspart, ksum);
  ctx_mfma_kernel<<<dim3(32, 8), blk, 0, stream>>>(vT, kpT, part);
  ctx_reduce_kernel<<<960, blk, 0, stream>>>(part, ksum, ctxpad);

  gemm_kernel<128, 96, 32, 96, EPI_CTX><<<dim3(64, 1, 8), blk, 0, stream>>>(
      qp, NFP, (long)N_SEQ * NFP, ctxpad, NFP, 96 * NFP, attn, 512, 64, NFP,
      nullptr, nullptr, 0);

  // WO: 512 blocks (BN=64)
  gemm_kernel<128, 64, 64, 32, EPI_BIAS_RES_F32><<<dim3(64, 8, 1), blk, 0, stream>>>(
      attn, 512, 0, wot, 512, 0, xb, 512, 0, 512, wob, x, 512);

  ln_kernel<<<N_SEQ, blk, 0, stream>>>(xb, ln2g, ln2b, h2);

  // FFN1: 1024 blocks
  gemm_kernel<128, 128, 64, 64, EPI_BIAS_GELU><<<dim3(64, 16, 1), blk, 0, stream>>>(
      h2, 512, 0, w1t, 512, 0, gbf, 2048, 0, 512, b1, nullptr, 0);

  // FFN2: 512 blocks (BN=64)
  gemm_kernel<128, 64, 64, 32, EPI_BIAS_RES_F32><<<dim3(64, 8, 1), blk, 0, stream>>>(
      gbf, 2048, 0, w2t, 2048, 0, d_out, 512, 0, 2048, b2, xb, 512);
}

// Round 6
// 214.899 us; speedup vs baseline: 1.2174x; 1.0927x over previous
//
#include <hip/hip_runtime.h>
#include <math.h>

// ---------------------------------------------------------------------------
// Performer encoder layer, MI355X round-6: fused attention chain.
//  - attn_fused: phi(q) + qp@ctx + dinv in one kernel (qp never materialized)
//  - ctx_fused:  phi(k) + kp^T v + colsums in one kernel (kpT never materialized)
// N=8192, D=512, H=8, DH=64, NF=266 (padded to NFP=320 = 5*64).
// Workspace layout (bytes):
//   0         wtqkv  bf16 [1536][512]
//   1572864   wot    bf16 [512][512]
//   2097152   w1t    bf16 [2048][512]
//   4194304   w2t    bf16 [512][2048]
//   6291456   projb  bf16 [320][64]
//   6332416   h_bf   bf16 [8192][512]     (reused as attn_bf)
//   14721024  qkv    bf16 [8192][1536]    (reused as h2_bf)
//   124297216 mk     u32  [8]
//   124297472 vT     bf16 [8][64][8192]
//   132686080 part   f32  [8][32][64][320]
//   153657600 kspart f32  [8][32][320]
//   154968320 ksum   f32  [8][320]
//   154978560 ctxpad bf16 [8][96][320]  (rows 0-63 ctx^T, row 64 ksum, 65+ 0)
//   130468096 gbf    bf16 [8192][2048]  (overlaps vT/part/..., lifetimes disjoint)
//   xb (f32 [8192][512]) lives in d_out.
// ---------------------------------------------------------------------------

typedef __attribute__((ext_vector_type(8))) short bf16x8;
typedef __attribute__((ext_vector_type(4))) float f32x4;

#define N_SEQ 8192
#define DMODEL 512
#define DQKV 1536
#define NHEAD 8
#define DHEAD 64
#define NF 266
#define NFP 320
#define PEPS 1e-4f
#define LNEPS 1e-5f
#define RATIO 0.06131393694f

__device__ __forceinline__ unsigned short f2bf(float f) {
  unsigned u = __float_as_uint(f);
  u += 0x7FFFu + ((u >> 16) & 1u);
  return (unsigned short)(u >> 16);
}
__device__ __forceinline__ float bf2f(unsigned short b) {
  return __uint_as_float(((unsigned)b) << 16);
}
__device__ __forceinline__ unsigned enc_f32(float f) {
  unsigned i = __float_as_uint(f);
  return (i & 0x80000000u) ? ~i : (i | 0x80000000u);
}
__device__ __forceinline__ float dec_f32(unsigned u) {
  return (u & 0x80000000u) ? __uint_as_float(u & 0x7FFFFFFFu) : __uint_as_float(~u);
}

__device__ __forceinline__ void g2l16(const void* g, void* l) {
  __builtin_amdgcn_global_load_lds(
      (const __attribute__((address_space(1))) void*)g,
      (__attribute__((address_space(3))) void*)l, 16, 0, 0);
}

// -------------------- small prep kernels --------------------

__global__ void init_mk_kernel(unsigned* mk) {
  if (threadIdx.x < NHEAD) mk[threadIdx.x] = 0x007FFFFFu;  // enc(-inf)
}

__global__ __launch_bounds__(256) void transpose_w_kernel(const float* __restrict__ src,
                                                          unsigned short* __restrict__ dst,
                                                          int R, int C) {
  __shared__ float tile[32][33];
  int c0 = blockIdx.x * 32, r0 = blockIdx.y * 32;
  int tx = threadIdx.x, ty = threadIdx.y;
  #pragma unroll
  for (int i = ty; i < 32; i += 8)
    tile[i][tx] = src[(long)(r0 + i) * C + c0 + tx];
  __syncthreads();
  #pragma unroll
  for (int i = ty; i < 32; i += 8)
    dst[(long)(c0 + i) * R + r0 + tx] = f2bf(tile[tx][i]);
}

__global__ void projb_kernel(const float* __restrict__ proj, unsigned short* __restrict__ pb) {
  int id = blockIdx.x * 256 + threadIdx.x;  // < 320*64
  int j = id >> 6;
  pb[id] = (j < NF) ? f2bf(proj[(long)j * 64 + (id & 63)] * 0.35355339059327373f)
                    : (unsigned short)0;
}

// v slice of qkv [8192][1536] -> vT [8][64][8192].
__global__ __launch_bounds__(256) void vtrans_kernel(const unsigned short* __restrict__ v,
                                                     unsigned short* __restrict__ vT) {
  __shared__ unsigned short tl[64][66];
  int h = blockIdx.z, n0 = blockIdx.y * 64;
  int tid = threadIdx.x;
  int i = tid >> 2, c0 = (tid & 3) * 16;
  const unsigned short* src = v + (long)(n0 + i) * DQKV + h * DHEAD + c0;
  uint4 u0 = *(const uint4*)src;
  uint4 u1 = *(const uint4*)(src + 8);
  const unsigned short* e0 = (const unsigned short*)&u0;
  const unsigned short* e1 = (const unsigned short*)&u1;
  #pragma unroll
  for (int k = 0; k < 8; ++k) { tl[i][c0 + k] = e0[k]; tl[i][c0 + 8 + k] = e1[k]; }
  __syncthreads();
  unsigned short tmp[16];
  #pragma unroll
  for (int k = 0; k < 16; ++k) tmp[k] = tl[c0 + k][i];
  unsigned short* dst = vT + ((long)h * DHEAD + i) * N_SEQ + n0 + c0;
  *(uint4*)dst = *(uint4*)&tmp[0];
  *(uint4*)(dst + 8) = *(uint4*)&tmp[8];
}

// -------------------- layernorm --------------------

__global__ __launch_bounds__(256) void ln_kernel(const float* __restrict__ x,
                                                 const float* __restrict__ g,
                                                 const float* __restrict__ b,
                                                 unsigned short* __restrict__ out) {
  __shared__ float sred[4];
  int row = blockIdx.x, t = threadIdx.x;
  float2 v = ((const float2*)(x + (long)row * DMODEL))[t];
  float s = v.x + v.y;
  #pragma unroll
  for (int m = 32; m >= 1; m >>= 1) s += __shfl_xor(s, m);
  if ((t & 63) == 0) sred[t >> 6] = s;
  __syncthreads();
  float mu = (sred[0] + sred[1] + sred[2] + sred[3]) * (1.0f / DMODEL);
  __syncthreads();
  float d0 = v.x - mu, d1 = v.y - mu;
  float q = d0 * d0 + d1 * d1;
  #pragma unroll
  for (int m = 32; m >= 1; m >>= 1) q += __shfl_xor(q, m);
  if ((t & 63) == 0) sred[t >> 6] = q;
  __syncthreads();
  float var = (sred[0] + sred[1] + sred[2] + sred[3]) * (1.0f / DMODEL);
  float inv = rsqrtf(var + LNEPS);
  int c = t * 2;
  unsigned short o0 = f2bf(d0 * inv * g[c] + b[c]);
  unsigned short o1 = f2bf(d1 * inv * g[c + 1] + b[c + 1]);
  ((unsigned*)(out + (long)row * DMODEL))[t] = ((unsigned)o1 << 16) | o0;
}

enum { EPI_BF16 = 0, EPI_BIAS_RES_F32 = 2, EPI_BIAS_GELU = 3 };

// -------------------- double-buffered 128-tile 4-wave GEMM --------------------

template <int BM, int BN, int WM, int WN, int EPI>
__global__ __launch_bounds__(256) void gemm_kernel(
    const unsigned short* __restrict__ A, int lda,
    const unsigned short* __restrict__ Bt, int ldb,
    void* __restrict__ Cv, int ldc,
    int K,
    const float* __restrict__ bias,
    const float* __restrict__ res, int ldr) {
  static_assert((BM / WM) * (BN / WN) == 4, "need 4 waves");
  constexpr int MR = WM / 16, NR = WN / 16;
  constexpr int WNN = BN / WN;
  constexpr int AIT = BM * 8 / 256;
  constexpr int BIT = BN * 8 / 256;
  const int tid = threadIdx.x;
  const int wave = tid >> 6, lane = tid & 63;
  const int lr = lane & 15, lg = lane >> 4;
  const int wr = wave / WNN, wc = wave % WNN;
  const int m0 = blockIdx.x * BM, n0 = blockIdx.y * BN;

  __shared__ uint4 a_s[2][BM * 8];
  __shared__ uint4 b_s[2][BN * 8];

  const unsigned short* asrc[AIT];
  #pragma unroll
  for (int e = 0; e < AIT; ++e) {
    int chunk = e * 256 + tid;
    int r = chunk >> 3, c = chunk & 7;
    asrc[e] = A + (long)(m0 + r) * lda + (c ^ (r & 7)) * 8;
  }
  const unsigned short* bsrc[BIT];
  #pragma unroll
  for (int e = 0; e < BIT; ++e) {
    int chunk = e * 256 + tid;
    int r = chunk >> 3, c = chunk & 7;
    bsrc[e] = Bt + (long)(n0 + r) * ldb + (c ^ (r & 7)) * 8;
  }
  const int wbase = tid & 192;

  f32x4 acc[MR][NR] = {};

  auto stage = [&](int buf, int t) {
    #pragma unroll
    for (int e = 0; e < AIT; ++e)
      g2l16(asrc[e] + t * 64, &a_s[buf][e * 256 + wbase]);
    #pragma unroll
    for (int e = 0; e < BIT; ++e)
      g2l16(bsrc[e] + t * 64, &b_s[buf][e * 256 + wbase]);
  };
  auto compute = [&](int buf) {
    #pragma unroll
    for (int ks = 0; ks < 2; ++ks) {
      bf16x8 af[MR], bv[NR];
      #pragma unroll
      for (int i = 0; i < MR; ++i) {
        int r = wr * WM + i * 16 + lr;
        af[i] = *(const bf16x8*)&a_s[buf][r * 8 + ((ks * 4 + lg) ^ (r & 7))];
      }
      #pragma unroll
      for (int j = 0; j < NR; ++j) {
        int r = wc * WN + j * 16 + lr;
        bv[j] = *(const bf16x8*)&b_s[buf][r * 8 + ((ks * 4 + lg) ^ (r & 7))];
      }
      #pragma unroll
      for (int i = 0; i < MR; ++i)
        #pragma unroll
        for (int j = 0; j < NR; ++j)
          acc[i][j] = __builtin_amdgcn_mfma_f32_16x16x32_bf16(af[i], bv[j], acc[i][j], 0, 0, 0);
    }
  };

  const int NT = K >> 6;
  stage(0, 0);
  __syncthreads();
  int cur = 0;
  for (int t = 0; t < NT - 1; ++t) {
    stage(cur ^ 1, t + 1);
    compute(cur);
    __syncthreads();
    cur ^= 1;
  }
  compute(cur);

  #pragma unroll
  for (int i = 0; i < MR; ++i) {
    #pragma unroll
    for (int j = 0; j < NR; ++j) {
      int gn = n0 + wc * WN + j * 16 + lr;
      #pragma unroll
      for (int rg = 0; rg < 4; ++rg) {
        int gm = m0 + wr * WM + i * 16 + lg * 4 + rg;
        float v = acc[i][j][rg];
        if (EPI == EPI_BF16) {
          ((unsigned short*)Cv)[(long)gm * ldc + gn] = f2bf(v);
        } else if (EPI == EPI_BIAS_RES_F32) {
          v += bias[gn] + res[(long)gm * ldr + gn];
          ((float*)Cv)[(long)gm * ldc + gn] = v;
        } else if (EPI == EPI_BIAS_GELU) {
          v += bias[gn];
          float t3 = 0.7978845608028654f * (v + 0.044715f * v * v * v);
          v = v / (1.0f + __expf(-2.0f * t3));  // 0.5v(1+tanh(t3))
          ((unsigned short*)Cv)[(long)gm * ldc + gn] = f2bf(v);
        }
      }
    }
  }
}

// -------------------- kmax: global max of dd(k) per head --------------------
// grid (128, 1, 8), 256 threads; dd GEMM K=64 then atomicMax(enc).

__global__ __launch_bounds__(256) void kmax_kernel(
    const unsigned short* __restrict__ Kp,  // qkv + 512 (k slice)
    const unsigned short* __restrict__ pb,
    unsigned* __restrict__ mk) {
  const int tid = threadIdx.x;
  const int wave = tid >> 6, lane = tid & 63;
  const int lr = lane & 15, lg = lane >> 4;
  const int h = blockIdx.z;
  const int m0 = blockIdx.x * 64;

  __shared__ uint4 a_s4[512];
  __shared__ uint4 b_s4[2560];
  __shared__ float sred[4];

  const unsigned short* Aq = Kp + (long)m0 * DQKV + h * DHEAD;
  const int wbase = tid & 192;

  #pragma unroll
  for (int e = 0; e < 2; ++e) {
    int chunk = e * 256 + tid;
    int r = chunk >> 3, c = chunk & 7;
    g2l16(Aq + (long)r * DQKV + (c ^ (r & 7)) * 8, a_s4 + e * 256 + wbase);
  }
  #pragma unroll
  for (int e = 0; e < 10; ++e) {
    int chunk = e * 256 + tid;
    int r = chunk >> 3, c = chunk & 7;
    g2l16(pb + (long)r * DHEAD + (c ^ (r & 7)) * 8, b_s4 + e * 256 + wbase);
  }
  __syncthreads();

  f32x4 acc[17] = {};
  #pragma unroll
  for (int ks = 0; ks < 2; ++ks) {
    int rA = wave * 16 + lr;
    bf16x8 af = *(const bf16x8*)&a_s4[rA * 8 + ((ks * 4 + lg) ^ (rA & 7))];
    #pragma unroll
    for (int j = 0; j < 17; ++j) {
      int rB = j * 16 + lr;
      bf16x8 bv = *(const bf16x8*)&b_s4[rB * 8 + ((ks * 4 + lg) ^ (rB & 7))];
      acc[j] = __builtin_amdgcn_mfma_f32_16x16x32_bf16(af, bv, acc[j], 0, 0, 0);
    }
  }

  float m = -3.0e38f;
  #pragma unroll
  for (int j = 0; j < 17; ++j) {
    bool valid = (j < 16) || (lr < 10);  // col = j*16+lr < 266
    if (valid) {
      #pragma unroll
      for (int rg = 0; rg < 4; ++rg) m = fmaxf(m, acc[j][rg]);
    }
  }
  #pragma unroll
  for (int s = 1; s < 64; s <<= 1) m = fmaxf(m, __shfl_xor(m, s));
  if (lane == 0) sred[wave] = m;
  __syncthreads();
  if (tid == 0) {
    float mm = fmaxf(fmaxf(sred[0], sred[1]), fmaxf(sred[2], sred[3]));
    atomicMax(&mk[h], enc_f32(mm));
  }
}

// -------------------- ctx_fused: phi(k) + kp^T v + colsums -------------------
// grid (32 kc, 8 h), 256 threads. Per block: 256 k-rows in 4 subs of 64.
// LDS: pbs 40KB (resident) | kstg 8KB | vstg 8KB | Pt 40KB  = 96KB.

__global__ __launch_bounds__(256) void ctx_fused_kernel(
    const unsigned short* __restrict__ Kp,   // qkv + 512
    const unsigned short* __restrict__ pb,   // [320][64]
    const unsigned short* __restrict__ vT,   // [8][64][8192]
    const unsigned* __restrict__ mk,
    float* __restrict__ part,                // [8][32][64][320]
    float* __restrict__ kspart) {            // [8][32][320]
  const int tid = threadIdx.x;
  const int wave = tid >> 6, lane = tid & 63;
  const int lr = lane & 15, lg = lane >> 4;
  const int kc = blockIdx.x, h = blockIdx.y;
  const int wbase = tid & 192;

  __shared__ uint4 smem[6144];
  uint4* pbs  = smem;          // 2560
  uint4* kstg = smem + 2560;   // 512
  uint4* vstg = smem + 3072;   // 512
  uint4* Pt   = smem + 3584;   // 2560

  // stage projb once
  #pragma unroll
  for (int e = 0; e < 10; ++e) {
    int chunk = e * 256 + tid;
    int r = chunk >> 3, c = chunk & 7;
    g2l16(pb + (long)r * DHEAD + (c ^ (r & 7)) * 8, pbs + e * 256 + wbase);
  }

  const float mh = dec_f32(mk[h]);
  f32x4 acc2[2][10] = {};   // ctx accumulator (persists across subs)
  float colacc[20];
  #pragma unroll
  for (int j = 0; j < 20; ++j) colacc[j] = 0.f;

  const int wr = wave >> 1, wc = wave & 1;

  for (int sub = 0; sub < 4; ++sub) {
    const int n0 = kc * 256 + sub * 64;
    __syncthreads();  // prior sub's reads of kstg/vstg/Pt complete
    // stage k rows [64][64] and vT tile [64][64]
    #pragma unroll
    for (int e = 0; e < 2; ++e) {
      int chunk = e * 256 + tid;
      int r = chunk >> 3, c = chunk & 7;
      g2l16(Kp + (long)(n0 + r) * DQKV + h * DHEAD + (c ^ (r & 7)) * 8,
            kstg + e * 256 + wbase);
      g2l16(vT + ((long)h * DHEAD + r) * N_SEQ + n0 + (c ^ (r & 7)) * 8,
            vstg + e * 256 + wbase);
    }
    __syncthreads();

    // dd GEMM: 4 waves x 16 rows, 320 cols; diag from staged rows
    f32x4 acc[20] = {};
    float qs = 0.f;
    #pragma unroll
    for (int ks = 0; ks < 2; ++ks) {
      int rA = wave * 16 + lr;
      bf16x8 af = *(const bf16x8*)&kstg[rA * 8 + ((ks * 4 + lg) ^ (rA & 7))];
      #pragma unroll
      for (int i = 0; i < 8; ++i) {
        float f = bf2f((unsigned short)af[i]);
        qs += f * f;
      }
      #pragma unroll
      for (int j = 0; j < 20; ++j) {
        int rB = j * 16 + lr;
        bf16x8 bv = *(const bf16x8*)&pbs[rB * 8 + ((ks * 4 + lg) ^ (rB & 7))];
        acc[j] = __builtin_amdgcn_mfma_f32_16x16x32_bf16(af, bv, acc[j], 0, 0, 0);
      }
    }
    qs += __shfl_xor(qs, 16);
    qs += __shfl_xor(qs, 32);
    float dg[4];
    #pragma unroll
    for (int rg = 0; rg < 4; ++rg) dg[rg] = 0.0625f * __shfl(qs, lg * 4 + rg);

    __syncthreads();  // dd reads of kstg/pbs done; prev Pt reads done (loop-top sync)

    // exp + transpose into Pt ([320 feat rows][64 n]) + colsum accumulate
    unsigned short* Ptu = (unsigned short*)Pt;
    const int nrow = wave * 16 + lg * 4;  // + rg
    #pragma unroll
    for (int j = 0; j < 20; ++j) {
      int colj = j * 16 + lr;
      #pragma unroll
      for (int rg = 0; rg < 4; ++rg) {
        float v = 0.f;
        if (colj < NF) v = RATIO * (__expf(acc[j][rg] - dg[rg] - mh) + PEPS);
        colacc[j] += v;
        int nr = nrow + rg;
        int idx = ((colj * 8 + ((nr >> 3) ^ (colj & 7))) << 3) + (nr & 7);
        Ptu[idx] = f2bf(v);
      }
    }
    __syncthreads();

    // ctx MFMA: C[64 d][320 j] += vT_sub^ * Pt
    #pragma unroll
    for (int ks = 0; ks < 2; ++ks) {
      bf16x8 af[2], bv[10];
      #pragma unroll
      for (int i = 0; i < 2; ++i) {
        int r = wr * 32 + i * 16 + lr;
        af[i] = *(const bf16x8*)&vstg[r * 8 + ((ks * 4 + lg) ^ (r & 7))];
      }
      #pragma unroll
      for (int j = 0; j < 10; ++j) {
        int r = wc * 160 + j * 16 + lr;
        bv[j] = *(const bf16x8*)&Pt[r * 8 + ((ks * 4 + lg) ^ (r & 7))];
      }
      #pragma unroll
      for (int i = 0; i < 2; ++i)
        #pragma unroll
        for (int j = 0; j < 10; ++j)
          acc2[i][j] = __builtin_amdgcn_mfma_f32_16x16x32_bf16(af[i], bv[j], acc2[i][j], 0, 0, 0);
    }
  }

  // write ctx partials
  float* pbase = part + ((long)(h * 32 + kc)) * 64 * NFP;
  #pragma unroll
  for (int i = 0; i < 2; ++i) {
    #pragma unroll
    for (int j = 0; j < 10; ++j) {
      int gn = wc * 160 + j * 16 + lr;
      #pragma unroll
      for (int rg = 0; rg < 4; ++rg) {
        int gm = wr * 32 + i * 16 + lg * 4 + rg;
        pbase[(long)gm * NFP + gn] = acc2[i][j][rg];
      }
    }
  }

  // colsum partials: reduce over lg within wave, cross-wave via LDS
  __syncthreads();  // ctx MFMA reads of Pt done; reuse as float scratch
  float* kls = (float*)Pt;  // [4][NFP]
  #pragma unroll
  for (int j = 0; j < 20; ++j) {
    float cs = colacc[j];
    cs += __shfl_xor(cs, 16);
    cs += __shfl_xor(cs, 32);
    if (lg == 0) kls[wave * NFP + j * 16 + lr] = cs;
  }
  __syncthreads();
  for (int c0 = tid; c0 < NFP; c0 += 256) {
    kspart[((long)(h * 32 + kc)) * NFP + c0] =
        kls[c0] + kls[NFP + c0] + kls[2 * NFP + c0] + kls[3 * NFP + c0];
  }
}

// -------------------- ksum reduce + ctxpad build --------------------

__global__ void ksum_red_kernel(const float* __restrict__ kspart,
                                float* __restrict__ ksum) {
  int i = blockIdx.x * 256 + threadIdx.x;
  if (i >= NHEAD * NFP) return;
  int h = i / NFP, j = i % NFP;
  float s = 0.f;
  #pragma unroll 4
  for (int b = 0; b < 32; ++b) s += kspart[((long)(h * 32 + b)) * NFP + j];
  ksum[i] = s;
}

__global__ void ctx_reduce_kernel(const float* __restrict__ part,
                                  const float* __restrict__ ksum,
                                  unsigned short* __restrict__ ctxpad) {
  int i = blockIdx.x * 256 + threadIdx.x;  // < 8*96*320 = 245760
  int h = i / (96 * NFP);
  int rem = i % (96 * NFP);
  int r = rem / NFP, j = rem % NFP;
  float s = 0.f;
  if (r < 64) {
    #pragma unroll 4
    for (int kc = 0; kc < 32; ++kc)
      s += part[((long)(h * 32 + kc)) * 64 * NFP + r * NFP + j];
  } else if (r == 64) {
    s = ksum[h * NFP + j];
  }
  ctxpad[i] = f2bf(s);
}

// -------------------- attn_fused: phi(q) + qp@ctx + dinv --------------------
// grid (128, 1, 8), 256 threads. Per block: 64 q-rows.
// LDS: stg 12KB (a_q then ctx tiles) | Pf 40KB (pb then P A-frags) = 52KB.

__global__ __launch_bounds__(256) void attn_fused_kernel(
    const unsigned short* __restrict__ Qp,   // qkv (q slice)
    const unsigned short* __restrict__ pb,   // [320][64]
    const unsigned short* __restrict__ ctxpad,  // [8][96][320]
    unsigned short* __restrict__ attn) {     // [8192][512]
  const int tid = threadIdx.x;
  const int wave = tid >> 6, lane = tid & 63;
  const int lr = lane & 15, lg = lane >> 4;
  const int h = blockIdx.z;
  const int m0 = blockIdx.x * 64;
  const int wbase = tid & 192;

  __shared__ uint4 smem[3328];
  uint4* stg = smem;         // 768 (phase1: a_q in first 512; phase2: ctx tile)
  uint4* Pf  = smem + 768;   // 2560 (phase1: pb; phase2: P A-frags)

  const unsigned short* Aq = Qp + (long)m0 * DQKV + h * DHEAD;

  #pragma unroll
  for (int e = 0; e < 2; ++e) {
    int chunk = e * 256 + tid;
    int r = chunk >> 3, c = chunk & 7;
    g2l16(Aq + (long)r * DQKV + (c ^ (r & 7)) * 8, stg + e * 256 + wbase);
  }
  #pragma unroll
  for (int e = 0; e < 10; ++e) {
    int chunk = e * 256 + tid;
    int r = chunk >> 3, c = chunk & 7;
    g2l16(pb + (long)r * DHEAD + (c ^ (r & 7)) * 8, Pf + e * 256 + wbase);
  }
  __syncthreads();

  // dd GEMM + diag
  f32x4 acc[20] = {};
  float qs = 0.f;
  #pragma unroll
  for (int ks = 0; ks < 2; ++ks) {
    int rA = wave * 16 + lr;
    bf16x8 af = *(const bf16x8*)&stg[rA * 8 + ((ks * 4 + lg) ^ (rA & 7))];
    #pragma unroll
    for (int i = 0; i < 8; ++i) {
      float f = bf2f((unsigned short)af[i]);
      qs += f * f;
    }
    #pragma unroll
    for (int j = 0; j < 20; ++j) {
      int rB = j * 16 + lr;
      bf16x8 bv = *(const bf16x8*)&Pf[rB * 8 + ((ks * 4 + lg) ^ (rB & 7))];
      acc[j] = __builtin_amdgcn_mfma_f32_16x16x32_bf16(af, bv, acc[j], 0, 0, 0);
    }
  }
  qs += __shfl_xor(qs, 16);
  qs += __shfl_xor(qs, 32);
  float dg[4];
  #pragma unroll
  for (int rg = 0; rg < 4; ++rg) dg[rg] = 0.0625f * __shfl(qs, lg * 4 + rg);

  // per-row max over valid cols
  float mrow[4];
  #pragma unroll
  for (int rg = 0; rg < 4; ++rg) mrow[rg] = -3.0e38f;
  #pragma unroll
  for (int j = 0; j < 17; ++j) {
    bool valid = (j < 16) || (lr < 10);
    if (valid) {
      #pragma unroll
      for (int rg = 0; rg < 4; ++rg) mrow[rg] = fmaxf(mrow[rg], acc[j][rg]);
    }
  }
  #pragma unroll
  for (int s = 1; s < 16; s <<= 1)
    #pragma unroll
    for (int rg = 0; rg < 4; ++rg) mrow[rg] = fmaxf(mrow[rg], __shfl_xor(mrow[rg], s));

  __syncthreads();  // all dd reads done; Pf reusable

  // exp + transpose P into A-frag layout: 5 tiles of [64 rows][64 k]
  unsigned short* Pu = (unsigned short*)Pf;
  const int prow = wave * 16 + lg * 4;  // + rg
  #pragma unroll
  for (int j = 0; j < 20; ++j) {
    int col = j * 16 + lr;
    int kk = col >> 6, cc = (col >> 3) & 7;
    #pragma unroll
    for (int rg = 0; rg < 4; ++rg) {
      float v = 0.f;
      if (col < NF) v = RATIO * (__expf(acc[j][rg] - dg[rg] - mrow[rg]) + PEPS);
      int rw = prow + rg;
      int idx = ((kk * 512 + rw * 8 + (cc ^ (rw & 7))) << 3) + (col & 7);
      Pu[idx] = f2bf(v);
    }
  }
  __syncthreads();

  // GEMM2: C[64 rows][96] = P[64][320] x ctxpad_h[96][320]^T
  const unsigned short* Ch = ctxpad + (long)h * 96 * NFP;
  f32x4 acc2[6] = {};
  for (int kk = 0; kk < 5; ++kk) {
    #pragma unroll
    for (int e = 0; e < 3; ++e) {
      int chunk = e * 256 + tid;
      int r = chunk >> 3, c = chunk & 7;
      g2l16(Ch + (long)r * NFP + kk * 64 + (c ^ (r & 7)) * 8, stg + e * 256 + wbase);
    }
    __syncthreads();
    #pragma unroll
    for (int ks = 0; ks < 2; ++ks) {
      int rA = wave * 16 + lr;
      bf16x8 af = *(const bf16x8*)&Pf[kk * 512 + rA * 8 + ((ks * 4 + lg) ^ (rA & 7))];
      #pragma unroll
      for (int j = 0; j < 6; ++j) {
        int rB = j * 16 + lr;
        bf16x8 bv = *(const bf16x8*)&stg[rB * 8 + ((ks * 4 + lg) ^ (rB & 7))];
        acc2[j] = __builtin_amdgcn_mfma_f32_16x16x32_bf16(af, bv, acc2[j], 0, 0, 0);
      }
    }
    __syncthreads();
  }

  // epilogue: divide by d = col 64, write attn
  #pragma unroll
  for (int rg = 0; rg < 4; ++rg) {
    float dv = __shfl(acc2[4][rg], lane & 48);  // col 64 (lr==0)
    float inv = 1.0f / dv;
    int gm = m0 + wave * 16 + lg * 4 + rg;
    #pragma unroll
    for (int j = 0; j < 4; ++j) {
      attn[(long)gm * DMODEL + h * DHEAD + j * 16 + lr] = f2bf(acc2[j][rg] * inv);
    }
  }
}

// -------------------- launch --------------------

extern "C" void kernel_launch(void* const* d_in, const int* in_sizes, int n_in,
                              void* d_out, int out_size, void* d_ws, size_t ws_size,
                              hipStream_t stream) {
  const float* x    = (const float*)d_in[0];
  const float* proj = (const float*)d_in[1];
  const float* ln1g = (const float*)d_in[2];
  const float* ln1b = (const float*)d_in[3];
  const float* wq   = (const float*)d_in[4];
  const float* wk   = (const float*)d_in[5];
  const float* wv   = (const float*)d_in[6];
  const float* wo   = (const float*)d_in[7];
  const float* wob  = (const float*)d_in[8];
  const float* ln2g = (const float*)d_in[9];
  const float* ln2b = (const float*)d_in[10];
  const float* w1   = (const float*)d_in[11];
  const float* b1   = (const float*)d_in[12];
  const float* w2   = (const float*)d_in[13];
  const float* b2   = (const float*)d_in[14];

  char* ws = (char*)d_ws;
  unsigned short* wtqkv = (unsigned short*)(ws + 0);
  unsigned short* wot   = (unsigned short*)(ws + 1572864);
  unsigned short* w1t   = (unsigned short*)(ws + 2097152);
  unsigned short* w2t   = (unsigned short*)(ws + 4194304);
  unsigned short* pb    = (unsigned short*)(ws + 6291456);
  unsigned short* h_bf  = (unsigned short*)(ws + 6332416);
  unsigned short* qkv   = (unsigned short*)(ws + 14721024);
  unsigned* mk          = (unsigned*)(ws + 124297216);
  unsigned short* vT    = (unsigned short*)(ws + 124297472);
  float* part           = (float*)(ws + 132686080);
  float* kspart         = (float*)(ws + 153657600);
  float* ksum           = (float*)(ws + 154968320);
  unsigned short* ctxpad= (unsigned short*)(ws + 154978560);
  unsigned short* gbf   = (unsigned short*)(ws + 130468096);
  unsigned short* attn  = h_bf;  // reuse (h_bf dead after QKV GEMM)
  unsigned short* h2    = qkv;   // reuse (qkv dead after attn_fused)
  float* xb             = (float*)d_out;

  dim3 blk(256);

  transpose_w_kernel<<<dim3(16, 16), dim3(32, 8), 0, stream>>>(wq, wtqkv, 512, 512);
  transpose_w_kernel<<<dim3(16, 16), dim3(32, 8), 0, stream>>>(wk, wtqkv + 262144, 512, 512);
  transpose_w_kernel<<<dim3(16, 16), dim3(32, 8), 0, stream>>>(wv, wtqkv + 524288, 512, 512);
  transpose_w_kernel<<<dim3(16, 16), dim3(32, 8), 0, stream>>>(wo, wot, 512, 512);
  transpose_w_kernel<<<dim3(64, 16), dim3(32, 8), 0, stream>>>(w1, w1t, 512, 2048);
  transpose_w_kernel<<<dim3(16, 64), dim3(32, 8), 0, stream>>>(w2, w2t, 2048, 512);
  projb_kernel<<<80, blk, 0, stream>>>(proj, pb);
  init_mk_kernel<<<1, 64, 0, stream>>>(mk);

  ln_kernel<<<N_SEQ, blk, 0, stream>>>(x, ln1g, ln1b, h_bf);

  // QKV: one GEMM, C = qkv [8192][1536]  (768 blocks)
  gemm_kernel<128, 128, 64, 64, EPI_BF16><<<dim3(64, 12), blk, 0, stream>>>(
      h_bf, 512, wtqkv, 512, qkv, DQKV, 512, nullptr, nullptr, 0);

  vtrans_kernel<<<dim3(1, 128, 8), blk, 0, stream>>>(qkv + 1024, vT);

  kmax_kernel<<<dim3(128, 1, 8), blk, 0, stream>>>(qkv + 512, pb, mk);

  ctx_fused_kernel<<<dim3(32, 8), blk, 0, stream>>>(qkv + 512, pb, vT, mk, part, kspart);
  ksum_red_kernel<<<10, blk, 0, stream>>>(kspart, ksum);
  ctx_reduce_kernel<<<960, blk, 0, stream>>>(part, ksum, ctxpad);

  attn_fused_kernel<<<dim3(128, 1, 8), blk, 0, stream>>>(qkv, pb, ctxpad, attn);

  // WO: 512 blocks (BN=64)
  gemm_kernel<128, 64, 64, 32, EPI_BIAS_RES_F32><<<dim3(64, 8), blk, 0, stream>>>(
      attn, 512, wot, 512, xb, 512, 512, wob, x, 512);

  ln_kernel<<<N_SEQ, blk, 0, stream>>>(xb, ln2g, ln2b, h2);

  // FFN1: 1024 blocks
  gemm_kernel<128, 128, 64, 64, EPI_BIAS_GELU><<<dim3(64, 16), blk, 0, stream>>>(
      h2, 512, w1t, 512, gbf, 2048, 512, b1, nullptr, 0);

  // FFN2: 512 blocks (BN=64)
  gemm_kernel<128, 64, 64, 32, EPI_BIAS_RES_F32><<<dim3(64, 8), blk, 0, stream>>>(
      gbf, 2048, w2t, 2048, d_out, 512, 2048, b2, xb, 512);
}